// Round 1
// baseline (297.217 us; speedup 1.0000x reference)
//
#include <hip/hip_runtime.h>
#include <math.h>

#define IOU_TH 0.5f
#define EPSF 1e-6f
#define GPER 8

__device__ __forceinline__ float sl1(float x) {
    float ax = fabsf(x);
    return ax < 1.f ? 0.5f * x * x : ax - 0.5f;
}

// ---------------- kernel 2: best anchor per (b,g) (argmax over A, first occurrence) ----
__global__ __launch_bounds__(256) void kBestAnchor(
    const float4* __restrict__ anchors, const float4* __restrict__ gt,
    int* __restrict__ forced, int A, int G)
{
    int nchunk = G / GPER;
    int b = blockIdx.x / nchunk;
    int g0 = (blockIdx.x % nchunk) * GPER;
    float4 gb[GPER]; float ga[GPER];
#pragma unroll
    for (int j = 0; j < GPER; ++j) {
        gb[j] = gt[(size_t)b * G + g0 + j];
        ga[j] = (gb[j].z - gb[j].x) * (gb[j].w - gb[j].y);
    }
    float bi[GPER], bd[GPER]; int bx[GPER];
#pragma unroll
    for (int j = 0; j < GPER; ++j) { bi[j] = -1.f; bd[j] = 1.f; bx[j] = 0; }
    for (int a = threadIdx.x; a < A; a += 256) {
        float4 ab = anchors[a];
        float aa = (ab.z - ab.x) * (ab.w - ab.y);
#pragma unroll
        for (int j = 0; j < GPER; ++j) {
            float wx = fmaxf(fminf(ab.z, gb[j].z) - fmaxf(ab.x, gb[j].x), 0.f);
            float wy = fmaxf(fminf(ab.w, gb[j].w) - fmaxf(ab.y, gb[j].y), 0.f);
            float inter = wx * wy;
            float den = aa + ga[j] - inter + EPSF;
            // iou_new > iou_best  <=>  inter*bd > bi*den  (den,bd > 0); strict > keeps first idx
            if (inter * bd[j] > bi[j] * den) { bi[j] = inter; bd[j] = den; bx[j] = a; }
        }
    }
    int lane = threadIdx.x & 63, wv = threadIdx.x >> 6;
    __shared__ float ri[4][GPER], rd[4][GPER]; __shared__ int rx[4][GPER];
#pragma unroll
    for (int j = 0; j < GPER; ++j) {
        float ci = bi[j], cd = bd[j]; int cx = bx[j];
        for (int off = 32; off > 0; off >>= 1) {
            float oi = __shfl_down(ci, off);
            float od = __shfl_down(cd, off);
            int   ox = __shfl_down(cx, off);
            if (lane + off < 64) {
                float lp = oi * cd, rp = ci * od;
                if (lp > rp || (lp == rp && ox < cx)) { ci = oi; cd = od; cx = ox; }
            }
        }
        if (lane == 0) { ri[wv][j] = ci; rd[wv][j] = cd; rx[wv][j] = cx; }
    }
    __syncthreads();
    if (threadIdx.x < GPER) {
        int j = threadIdx.x;
        float ci = ri[0][j], cd = rd[0][j]; int cx = rx[0][j];
        for (int w = 1; w < 4; ++w) {
            float oi = ri[w][j], od = rd[w][j]; int ox = rx[w][j];
            float lp = oi * cd, rp = ci * od;
            if (lp > rp || (lp == rp && ox < cx)) { ci = oi; cd = od; cx = ox; }
        }
        forced[(size_t)b * G + g0 + j] = cx;
    }
}

// ---------------- kernel 3: per-anchor match + losses ----------------
__global__ __launch_bounds__(256) void kMain(
    const float4* __restrict__ bbox, const float* __restrict__ conf,
    const float4* __restrict__ anchors, const float4* __restrict__ gt,
    const int* __restrict__ forced,
    float* __restrict__ neg,
    float* __restrict__ accLoc, float* __restrict__ accFpos,
    float* __restrict__ accSiou, int* __restrict__ accNpos,
    int A, int G)
{
    __shared__ float4 sGt[128]; __shared__ float sGa[128]; __shared__ int sF[128];
    int b = blockIdx.y;
    if (threadIdx.x < G) {
        float4 g = gt[(size_t)b * G + threadIdx.x];
        sGt[threadIdx.x] = g;
        sGa[threadIdx.x] = (g.z - g.x) * (g.w - g.y);
        sF[threadIdx.x] = forced[(size_t)b * G + threadIdx.x];
    }
    __syncthreads();
    int a = blockIdx.x * 256 + threadIdx.x;   // A % 256 == 0
    float4 an = anchors[a];
    float aa = (an.z - an.x) * (an.w - an.y);
    // argmax over g of IoU(anchor, gt_g), first occurrence, division-free
    float bi, bd; int bx = 0;
    {
        float4 g = sGt[0];
        float wx = fmaxf(fminf(an.z, g.z) - fmaxf(an.x, g.x), 0.f);
        float wy = fmaxf(fminf(an.w, g.w) - fmaxf(an.y, g.y), 0.f);
        float inter = wx * wy;
        bi = inter; bd = aa + sGa[0] - inter + EPSF;
    }
    for (int g = 1; g < G; ++g) {
        float4 gg = sGt[g];
        float wx = fmaxf(fminf(an.z, gg.z) - fmaxf(an.x, gg.x), 0.f);
        float wy = fmaxf(fminf(an.w, gg.w) - fmaxf(an.y, gg.y), 0.f);
        float inter = wx * wy;
        float den = aa + sGa[g] - inter + EPSF;
        if (inter * bd > bi * den) { bi = inter; bd = den; bx = g; }
    }
    float best_iou = bi / bd;
    bool pos = best_iou > IOU_TH;
    bool forcedHit = false;
    for (int g = 0; g < G; ++g) forcedHit |= (sF[g] == a);
    pos = pos || forcedHit;

    float4 p4 = bbox[(size_t)b * A + a];
    float4 m = sGt[bx];
    float pa = (p4.z - p4.x) * (p4.w - p4.y);
    float ta = (m.z - m.x) * (m.w - m.y);
    float wx = fmaxf(fminf(p4.z, m.z) - fmaxf(p4.x, m.x), 0.f);
    float wy = fmaxf(fminf(p4.w, m.w) - fmaxf(p4.y, m.y), 0.f);
    float inter = wx * wy;
    float a_iou = inter / (pa + ta - inter + EPSF);
    // giou (faithful to source incl. nonstandard union)
    float ex = fmaxf(fmaxf(p4.z, m.z) - fminf(p4.x, m.x), 0.f);
    float ey = fmaxf(fmaxf(p4.w, m.w) - fminf(p4.y, m.y), 0.f);
    float enc = ex * ey + EPSF;
    float uni = pa + ta - a_iou * pa * ta;
    float gl = 1.f - (a_iou - (enc - uni) / enc);
    float cl = sl1((p4.x + p4.z) * 0.5f - (m.x + m.z) * 0.5f)
             + sl1((p4.y + p4.w) * 0.5f - (m.y + m.w) * 0.5f);
    float szl = sl1((p4.z - p4.x) - (m.z - m.x)) + sl1((p4.w - p4.y) - (m.w - m.y));
    float box_loss = 0.5f * (cl + szl) + 0.5f * gl;
    // focal
    float cp = conf[(size_t)b * A + a];
    float t = pos ? a_iou : 0.f;
    float pcl = fminf(fmaxf(cp, 1e-7f), 1.f - 1e-7f);
    float bce = -(t * logf(pcl) + (1.f - t) * log1pf(-pcl));
    float pt = (t > 0.f) ? cp : (1.f - cp);
    float om = 1.f - pt;
    float f = om * om * ((t > 0.f) ? 0.25f : 0.75f) * bce;

    neg[(size_t)b * A + a] = pos ? 0.f : f;
    float vloc = pos ? box_loss : 0.f;
    float vf = pos ? f : 0.f;
    float vs = pos ? a_iou : 0.f;
    int vn = pos ? 1 : 0;
    int lane = threadIdx.x & 63;
    for (int off = 32; off > 0; off >>= 1) {
        vloc += __shfl_down(vloc, off);
        vf   += __shfl_down(vf, off);
        vs   += __shfl_down(vs, off);
        vn   += __shfl_down(vn, off);
    }
    if (lane == 0) {
        atomicAdd(&accLoc[b], vloc);
        atomicAdd(&accFpos[b], vf);
        atomicAdd(&accSiou[b], vs);
        atomicAdd(&accNpos[b], vn);
    }
}

// ---------------- kernel 4: exact top-k sum via 3-level radix select ----------------
__global__ __launch_bounds__(1024) void kSelect(
    const float* __restrict__ neg, const int* __restrict__ accNpos,
    const float* __restrict__ accFpos, float* __restrict__ accConf, int A)
{
    __shared__ unsigned int cnt[2048];
    __shared__ float sm[2048];
    __shared__ int sh_cut, sh_rem, sh_done;
    __shared__ float sh_sum;
    int b = blockIdx.x;
    const float* vb = neg + (size_t)b * A;
    int npos = accNpos[b];
    int k = min(npos * 3, A - npos);
    if (threadIdx.x == 0) { sh_sum = 0.f; sh_rem = k; }
    __syncthreads();
    bool done = (k <= 0);
    unsigned int pref = 0;
    int prevshift = 32;
    const int shifts[3] = {21, 10, 0};
    const int nbitsArr[3] = {11, 11, 10};
    for (int lvl = 0; lvl < 3; ++lvl) {
        if (done) break;
        int shift = shifts[lvl];
        int nb = 1 << nbitsArr[lvl];
        for (int i = threadIdx.x; i < 2048; i += 1024) { cnt[i] = 0u; sm[i] = 0.f; }
        if (threadIdx.x == 0) sh_done = 0;
        __syncthreads();
        for (int i = threadIdx.x; i < A; i += 1024) {
            float v = vb[i];
            unsigned int u = __float_as_uint(v);   // all values >= 0 -> bits monotonic
            if (lvl == 0 || (u >> prevshift) == pref) {
                unsigned int bin = (u >> shift) & (unsigned)(nb - 1);
                atomicAdd(&cnt[bin], 1u);
                atomicAdd(&sm[bin], v);
            }
        }
        __syncthreads();
        if (threadIdx.x < 64) {   // wave 0: suffix-scan from top bin down
            int lane = threadIdx.x;
            int kneed = sh_rem;
            unsigned int runc = 0; float runs = 0.f;
            bool found = false;
            for (int cb = nb / 64 - 1; cb >= 0 && !found; --cb) {
                unsigned int c = cnt[cb * 64 + lane];
                float s = sm[cb * 64 + lane];
                unsigned int sc = c; float ss = s;
                for (int off = 1; off < 64; off <<= 1) {
                    unsigned int oc = __shfl_down(sc, off);
                    float os = __shfl_down(ss, off);
                    if (lane + off < 64) { sc += oc; ss += os; }
                }
                unsigned int total_c = __shfl(sc, 0);
                float total_s = __shfl(ss, 0);
                unsigned int SC = runc + sc;   // count of values in bins >= this lane's bin
                unsigned long long mask = __ballot(SC >= (unsigned)kneed);
                if (mask != 0ull) {
                    found = true;
                    int cl = 63 - __clzll((long long)mask);   // highest bin with SC >= k
                    unsigned int sc_above = (cl < 63) ? __shfl(sc, cl + 1) : 0u;
                    float ss_above = (cl < 63) ? __shfl(ss, cl + 1) : 0.f;
                    unsigned int cbin = __shfl(c, cl);
                    float sbin = __shfl(s, cl);
                    unsigned int count_above = runc + sc_above;
                    float sum_above = runs + ss_above;
                    int rem2 = kneed - (int)count_above;   // 1..cbin
                    if (lane == 0) {
                        sh_sum += sum_above;
                        if ((int)cbin == rem2) { sh_sum += sbin; sh_done = 1; }
                        else { sh_rem = rem2; sh_cut = cb * 64 + cl; }
                    }
                } else {
                    runc += total_c; runs += total_s;
                }
            }
            if (!found && lane == 0) sh_done = 1;   // safety
        }
        __syncthreads();
        done = (sh_done != 0);
        if (!done) {
            pref = (pref << nbitsArr[lvl]) | (unsigned)sh_cut;
            prevshift = shift;
            if (lvl == 2) {   // 32 bits resolved: remaining values identical
                if (threadIdx.x == 0) sh_sum += (float)sh_rem * __uint_as_float(pref);
                done = true;
            }
        }
    }
    __syncthreads();
    if (threadIdx.x == 0) accConf[b] = sh_sum + accFpos[b];
}

// ---------------- kernel 5: final reduce ----------------
__global__ void kFinal(const float* __restrict__ accLoc, const float* __restrict__ accConf,
                       const float* __restrict__ accSiou, const int* __restrict__ accNpos,
                       float* __restrict__ out, int B)
{
    int lane = threadIdx.x;
    float loc = 0.f, cf = 0.f, si = 0.f; int np = 0;
    if (lane < B) { loc = accLoc[lane]; cf = accConf[lane]; si = accSiou[lane]; np = accNpos[lane]; }
    for (int off = 32; off > 0; off >>= 1) {
        loc += __shfl_down(loc, off);
        cf  += __shfl_down(cf, off);
        si  += __shfl_down(si, off);
        np  += __shfl_down(np, off);
    }
    if (lane == 0) {
        float denom = fmaxf(1.f, (float)np);
        float tl = loc / denom, tc = cf / denom;
        out[0] = tl + tc;
        out[1] = tc;
        out[2] = tl;
        out[3] = si / denom;
    }
}

extern "C" void kernel_launch(void* const* d_in, const int* in_sizes, int n_in,
                              void* d_out, int out_size, void* d_ws, size_t ws_size,
                              hipStream_t stream)
{
    const float4* bbox    = (const float4*)d_in[0];
    const float*  conf    = (const float*)d_in[1];
    const float4* anchors = (const float4*)d_in[2];
    const float4* gt      = (const float4*)d_in[3];
    int A = in_sizes[2] / 4;
    int B = in_sizes[1] / A;
    int G = in_sizes[3] / (4 * B);
    float* out = (float*)d_out;

    char* ws = (char*)d_ws;
    float* neg = (float*)ws;
    size_t off = (size_t)B * A * sizeof(float);
    int* forced = (int*)(ws + off); off += (size_t)B * G * sizeof(int);
    float* accLoc  = (float*)(ws + off); off += (size_t)B * sizeof(float);
    float* accFpos = (float*)(ws + off); off += (size_t)B * sizeof(float);
    float* accSiou = (float*)(ws + off); off += (size_t)B * sizeof(float);
    float* accConf = (float*)(ws + off); off += (size_t)B * sizeof(float);
    int*   accNpos = (int*)(ws + off);   off += (size_t)B * sizeof(int);

    hipMemsetAsync(accLoc, 0, 5 * (size_t)B * sizeof(float), stream);
    kBestAnchor<<<dim3(B * (G / GPER)), 256, 0, stream>>>(anchors, gt, forced, A, G);
    kMain<<<dim3(A / 256, B), 256, 0, stream>>>(bbox, conf, anchors, gt, forced, neg,
                                                accLoc, accFpos, accSiou, accNpos, A, G);
    kSelect<<<dim3(B), 1024, 0, stream>>>(neg, accNpos, accFpos, accConf, A);
    kFinal<<<1, 64, 0, stream>>>(accLoc, accConf, accSiou, accNpos, out, B);
}

// Round 2
// 155.224 us; speedup vs baseline: 1.9148x; 1.9148x over previous
//
#include <hip/hip_runtime.h>
#include <math.h>

#define IOU_TH 0.5f
#define EPSF 1e-6f
#define GPER 8
#define ASPLIT 8

__device__ __forceinline__ float sl1(float x) {
    float ax = fabsf(x);
    return ax < 1.f ? 0.5f * x * x : ax - 0.5f;
}

// ---------------- kernel 2: best anchor per (b,g), A split 8-way, merged via atomicMax ----
__global__ __launch_bounds__(256) void kBestAnchor(
    const float4* __restrict__ anchors, const float4* __restrict__ gt,
    unsigned long long* __restrict__ wsKey, int A, int G)
{
    int nch = G / GPER;
    int b   = blockIdx.x / (nch * ASPLIT);
    int r   = blockIdx.x % (nch * ASPLIT);
    int g0  = (r / ASPLIT) * GPER;
    int aChunk = A / ASPLIT;
    int a0  = (r % ASPLIT) * aChunk;

    float4 gb[GPER]; float ga[GPER];
#pragma unroll
    for (int j = 0; j < GPER; ++j) {
        gb[j] = gt[(size_t)b * G + g0 + j];
        ga[j] = (gb[j].z - gb[j].x) * (gb[j].w - gb[j].y);
    }
    float bi[GPER], bd[GPER]; int bx[GPER];
#pragma unroll
    for (int j = 0; j < GPER; ++j) { bi[j] = -1.f; bd[j] = 1.f; bx[j] = a0; }
    for (int a = a0 + threadIdx.x; a < a0 + aChunk; a += 256) {
        float4 ab = anchors[a];
        float aa = (ab.z - ab.x) * (ab.w - ab.y);
#pragma unroll
        for (int j = 0; j < GPER; ++j) {
            float wx = fmaxf(fminf(ab.z, gb[j].z) - fmaxf(ab.x, gb[j].x), 0.f);
            float wy = fmaxf(fminf(ab.w, gb[j].w) - fmaxf(ab.y, gb[j].y), 0.f);
            float inter = wx * wy;
            float den = aa + ga[j] - inter + EPSF;
            if (inter * bd[j] > bi[j] * den) { bi[j] = inter; bd[j] = den; bx[j] = a; }
        }
    }
    int lane = threadIdx.x & 63, wv = threadIdx.x >> 6;
    __shared__ float ri[4][GPER], rd[4][GPER]; __shared__ int rx[4][GPER];
#pragma unroll
    for (int j = 0; j < GPER; ++j) {
        float ci = bi[j], cd = bd[j]; int cx = bx[j];
        for (int off = 32; off > 0; off >>= 1) {
            float oi = __shfl_down(ci, off);
            float od = __shfl_down(cd, off);
            int   ox = __shfl_down(cx, off);
            if (lane + off < 64) {
                float lp = oi * cd, rp = ci * od;
                if (lp > rp || (lp == rp && ox < cx)) { ci = oi; cd = od; cx = ox; }
            }
        }
        if (lane == 0) { ri[wv][j] = ci; rd[wv][j] = cd; rx[wv][j] = cx; }
    }
    __syncthreads();
    if (threadIdx.x < GPER) {
        int j = threadIdx.x;
        float ci = ri[0][j], cd = rd[0][j]; int cx = rx[0][j];
        for (int w = 1; w < 4; ++w) {
            float oi = ri[w][j], od = rd[w][j]; int ox = rx[w][j];
            float lp = oi * cd, rp = ci * od;
            if (lp > rp || (lp == rp && ox < cx)) { ci = oi; cd = od; cx = ox; }
        }
        float iou = ci / cd;   // compare divided value across blocks (matches jnp semantics)
        unsigned long long key =
            ((unsigned long long)__float_as_uint(iou) << 32) | (unsigned int)(~(unsigned int)cx);
        atomicMax(&wsKey[(size_t)b * G + g0 + j], key);
    }
}

// ---------------- kernel 2b: decode winners -> per-anchor forced flag ----------------
__global__ void kForce(const unsigned long long* __restrict__ wsKey,
                       unsigned char* __restrict__ flag, int A, int G, int BG)
{
    int i = blockIdx.x * 256 + threadIdx.x;
    if (i < BG) {
        unsigned long long k = wsKey[i];
        unsigned int idx = ~(unsigned int)(k & 0xFFFFFFFFull);
        int b = i / G;
        flag[(size_t)b * A + idx] = 1;
    }
}

// ---------------- kernel 3: per-anchor match + losses ----------------
__global__ __launch_bounds__(256) void kMain(
    const float4* __restrict__ bbox, const float* __restrict__ conf,
    const float4* __restrict__ anchors, const float4* __restrict__ gt,
    const unsigned char* __restrict__ forcedFlag,
    float* __restrict__ neg,
    float* __restrict__ accLoc, float* __restrict__ accFpos,
    float* __restrict__ accSiou, int* __restrict__ accNpos,
    int A, int G)
{
    __shared__ float4 sGt[128];
    int b = blockIdx.y;
    if (threadIdx.x < G) sGt[threadIdx.x] = gt[(size_t)b * G + threadIdx.x];
    __syncthreads();
    int a = blockIdx.x * 256 + threadIdx.x;   // A % 256 == 0
    float4 an = anchors[a];
    float aa = (an.z - an.x) * (an.w - an.y);

    // argmax over g: 4 independent chains (g mod 4), group-of-4 LDS prefetch
    float bi[4], bd[4]; int bx[4];
#pragma unroll
    for (int c = 0; c < 4; ++c) { bi[c] = -1.f; bd[c] = 1.f; bx[c] = c; }
#pragma unroll 2
    for (int g = 0; g < G; g += 4) {
        float4 q0 = sGt[g], q1 = sGt[g + 1], q2 = sGt[g + 2], q3 = sGt[g + 3];
        {
            float gwa = (q0.z - q0.x) * (q0.w - q0.y);
            float wx = fmaxf(fminf(an.z, q0.z) - fmaxf(an.x, q0.x), 0.f);
            float wy = fmaxf(fminf(an.w, q0.w) - fmaxf(an.y, q0.y), 0.f);
            float inter = wx * wy;
            float den = aa + gwa - inter + EPSF;
            if (inter * bd[0] > bi[0] * den) { bi[0] = inter; bd[0] = den; bx[0] = g; }
        }
        {
            float gwa = (q1.z - q1.x) * (q1.w - q1.y);
            float wx = fmaxf(fminf(an.z, q1.z) - fmaxf(an.x, q1.x), 0.f);
            float wy = fmaxf(fminf(an.w, q1.w) - fmaxf(an.y, q1.y), 0.f);
            float inter = wx * wy;
            float den = aa + gwa - inter + EPSF;
            if (inter * bd[1] > bi[1] * den) { bi[1] = inter; bd[1] = den; bx[1] = g + 1; }
        }
        {
            float gwa = (q2.z - q2.x) * (q2.w - q2.y);
            float wx = fmaxf(fminf(an.z, q2.z) - fmaxf(an.x, q2.x), 0.f);
            float wy = fmaxf(fminf(an.w, q2.w) - fmaxf(an.y, q2.y), 0.f);
            float inter = wx * wy;
            float den = aa + gwa - inter + EPSF;
            if (inter * bd[2] > bi[2] * den) { bi[2] = inter; bd[2] = den; bx[2] = g + 2; }
        }
        {
            float gwa = (q3.z - q3.x) * (q3.w - q3.y);
            float wx = fmaxf(fminf(an.z, q3.z) - fmaxf(an.x, q3.x), 0.f);
            float wy = fmaxf(fminf(an.w, q3.w) - fmaxf(an.y, q3.y), 0.f);
            float inter = wx * wy;
            float den = aa + gwa - inter + EPSF;
            if (inter * bd[3] > bi[3] * den) { bi[3] = inter; bd[3] = den; bx[3] = g + 3; }
        }
    }
    // merge 4 chains (tie -> smaller g, preserving first-occurrence)
    float Bi = bi[0], Bd = bd[0]; int Bx = bx[0];
#pragma unroll
    for (int c = 1; c < 4; ++c) {
        float lp = bi[c] * Bd, rp = Bi * bd[c];
        if (lp > rp || (lp == rp && bx[c] < Bx)) { Bi = bi[c]; Bd = bd[c]; Bx = bx[c]; }
    }
    float best_iou = Bi / Bd;
    bool pos = (best_iou > IOU_TH) || (forcedFlag[(size_t)b * A + a] != 0);

    float4 p4 = bbox[(size_t)b * A + a];
    float4 m = sGt[Bx];
    float pa = (p4.z - p4.x) * (p4.w - p4.y);
    float ta = (m.z - m.x) * (m.w - m.y);
    float wx = fmaxf(fminf(p4.z, m.z) - fmaxf(p4.x, m.x), 0.f);
    float wy = fmaxf(fminf(p4.w, m.w) - fmaxf(p4.y, m.y), 0.f);
    float inter = wx * wy;
    float a_iou = inter / (pa + ta - inter + EPSF);
    float ex = fmaxf(fmaxf(p4.z, m.z) - fminf(p4.x, m.x), 0.f);
    float ey = fmaxf(fmaxf(p4.w, m.w) - fminf(p4.y, m.y), 0.f);
    float enc = ex * ey + EPSF;
    float uni = pa + ta - a_iou * pa * ta;
    float gl = 1.f - (a_iou - (enc - uni) / enc);
    float cl = sl1((p4.x + p4.z) * 0.5f - (m.x + m.z) * 0.5f)
             + sl1((p4.y + p4.w) * 0.5f - (m.y + m.w) * 0.5f);
    float szl = sl1((p4.z - p4.x) - (m.z - m.x)) + sl1((p4.w - p4.y) - (m.w - m.y));
    float box_loss = 0.5f * (cl + szl) + 0.5f * gl;
    float cp = conf[(size_t)b * A + a];
    float t = pos ? a_iou : 0.f;
    float pcl = fminf(fmaxf(cp, 1e-7f), 1.f - 1e-7f);
    float bce = -(t * logf(pcl) + (1.f - t) * log1pf(-pcl));
    float pt = (t > 0.f) ? cp : (1.f - cp);
    float om = 1.f - pt;
    float f = om * om * ((t > 0.f) ? 0.25f : 0.75f) * bce;

    neg[(size_t)b * A + a] = pos ? 0.f : f;
    float vloc = pos ? box_loss : 0.f;
    float vf = pos ? f : 0.f;
    float vs = pos ? a_iou : 0.f;
    int vn = pos ? 1 : 0;
    int lane = threadIdx.x & 63, wv = threadIdx.x >> 6;
    for (int off = 32; off > 0; off >>= 1) {
        vloc += __shfl_down(vloc, off);
        vf   += __shfl_down(vf, off);
        vs   += __shfl_down(vs, off);
        vn   += __shfl_down(vn, off);
    }
    __shared__ float red[4][3]; __shared__ int redN[4];
    if (lane == 0) { red[wv][0] = vloc; red[wv][1] = vf; red[wv][2] = vs; redN[wv] = vn; }
    __syncthreads();
    if (threadIdx.x == 0) {
        float sl = 0.f, sf = 0.f, ss = 0.f; int sn = 0;
#pragma unroll
        for (int w = 0; w < 4; ++w) { sl += red[w][0]; sf += red[w][1]; ss += red[w][2]; sn += redN[w]; }
        atomicAdd(&accLoc[b], sl);
        atomicAdd(&accFpos[b], sf);
        atomicAdd(&accSiou[b], ss);
        atomicAdd(&accNpos[b], sn);
    }
}

// ---------------- kernel 4: exact top-k sum via 3-level radix select ----------------
__global__ __launch_bounds__(1024) void kSelect(
    const float* __restrict__ neg, const int* __restrict__ accNpos,
    const float* __restrict__ accFpos, float* __restrict__ accConf, int A)
{
    __shared__ unsigned int cnt[2048];
    __shared__ float sm[2048];
    __shared__ int sh_cut, sh_rem, sh_done;
    __shared__ float sh_sum;
    int b = blockIdx.x;
    const float* vb = neg + (size_t)b * A;
    int npos = accNpos[b];
    int k = min(npos * 3, A - npos);
    if (threadIdx.x == 0) { sh_sum = 0.f; sh_rem = k; }
    __syncthreads();
    bool done = (k <= 0);
    unsigned int pref = 0;
    int prevshift = 32;
    const int shifts[3] = {21, 10, 0};
    const int nbitsArr[3] = {11, 11, 10};
    for (int lvl = 0; lvl < 3; ++lvl) {
        if (done) break;
        int shift = shifts[lvl];
        int nb = 1 << nbitsArr[lvl];
        for (int i = threadIdx.x; i < 2048; i += 1024) { cnt[i] = 0u; sm[i] = 0.f; }
        if (threadIdx.x == 0) sh_done = 0;
        __syncthreads();
        for (int i = threadIdx.x; i < A; i += 1024) {
            float v = vb[i];
            unsigned int u = __float_as_uint(v);   // all values >= 0 -> bits monotonic
            if (lvl == 0 || (u >> prevshift) == pref) {
                unsigned int bin = (u >> shift) & (unsigned)(nb - 1);
                atomicAdd(&cnt[bin], 1u);
                atomicAdd(&sm[bin], v);
            }
        }
        __syncthreads();
        if (threadIdx.x < 64) {   // wave 0: suffix-scan from top bin down
            int lane = threadIdx.x;
            int kneed = sh_rem;
            unsigned int runc = 0; float runs = 0.f;
            bool found = false;
            for (int cb = nb / 64 - 1; cb >= 0 && !found; --cb) {
                unsigned int c = cnt[cb * 64 + lane];
                float s = sm[cb * 64 + lane];
                unsigned int sc = c; float ss = s;
                for (int off = 1; off < 64; off <<= 1) {
                    unsigned int oc = __shfl_down(sc, off);
                    float os = __shfl_down(ss, off);
                    if (lane + off < 64) { sc += oc; ss += os; }
                }
                unsigned int total_c = __shfl(sc, 0);
                float total_s = __shfl(ss, 0);
                unsigned int SC = runc + sc;
                unsigned long long mask = __ballot(SC >= (unsigned)kneed);
                if (mask != 0ull) {
                    found = true;
                    int cl = 63 - __clzll((long long)mask);
                    unsigned int sc_above = (cl < 63) ? __shfl(sc, cl + 1) : 0u;
                    float ss_above = (cl < 63) ? __shfl(ss, cl + 1) : 0.f;
                    unsigned int cbin = __shfl(c, cl);
                    float sbin = __shfl(s, cl);
                    unsigned int count_above = runc + sc_above;
                    float sum_above = runs + ss_above;
                    int rem2 = kneed - (int)count_above;
                    if (lane == 0) {
                        sh_sum += sum_above;
                        if ((int)cbin == rem2) { sh_sum += sbin; sh_done = 1; }
                        else { sh_rem = rem2; sh_cut = cb * 64 + cl; }
                    }
                } else {
                    runc += total_c; runs += total_s;
                }
            }
            if (!found && lane == 0) sh_done = 1;
        }
        __syncthreads();
        done = (sh_done != 0);
        if (!done) {
            pref = (pref << nbitsArr[lvl]) | (unsigned)sh_cut;
            prevshift = shift;
            if (lvl == 2) {
                if (threadIdx.x == 0) sh_sum += (float)sh_rem * __uint_as_float(pref);
                done = true;
            }
        }
    }
    __syncthreads();
    if (threadIdx.x == 0) accConf[b] = sh_sum + accFpos[b];
}

// ---------------- kernel 5: final reduce ----------------
__global__ void kFinal(const float* __restrict__ accLoc, const float* __restrict__ accConf,
                       const float* __restrict__ accSiou, const int* __restrict__ accNpos,
                       float* __restrict__ out, int B)
{
    int lane = threadIdx.x;
    float loc = 0.f, cf = 0.f, si = 0.f; int np = 0;
    if (lane < B) { loc = accLoc[lane]; cf = accConf[lane]; si = accSiou[lane]; np = accNpos[lane]; }
    for (int off = 32; off > 0; off >>= 1) {
        loc += __shfl_down(loc, off);
        cf  += __shfl_down(cf, off);
        si  += __shfl_down(si, off);
        np  += __shfl_down(np, off);
    }
    if (lane == 0) {
        float denom = fmaxf(1.f, (float)np);
        float tl = loc / denom, tc = cf / denom;
        out[0] = tl + tc;
        out[1] = tc;
        out[2] = tl;
        out[3] = si / denom;
    }
}

extern "C" void kernel_launch(void* const* d_in, const int* in_sizes, int n_in,
                              void* d_out, int out_size, void* d_ws, size_t ws_size,
                              hipStream_t stream)
{
    const float4* bbox    = (const float4*)d_in[0];
    const float*  conf    = (const float*)d_in[1];
    const float4* anchors = (const float4*)d_in[2];
    const float4* gt      = (const float4*)d_in[3];
    int A = in_sizes[2] / 4;
    int B = in_sizes[1] / A;
    int G = in_sizes[3] / (4 * B);
    float* out = (float*)d_out;

    char* ws = (char*)d_ws;
    float* neg = (float*)ws;
    size_t off = (size_t)B * A * sizeof(float);
    unsigned char* forcedFlag = (unsigned char*)(ws + off);
    size_t flagOff = off;
    off += (size_t)B * A;                                   // byte flags
    unsigned long long* wsKey = (unsigned long long*)(ws + off);
    off += (size_t)B * G * sizeof(unsigned long long);
    float* accLoc  = (float*)(ws + off); off += (size_t)B * sizeof(float);
    float* accFpos = (float*)(ws + off); off += (size_t)B * sizeof(float);
    float* accSiou = (float*)(ws + off); off += (size_t)B * sizeof(float);
    float* accConf = (float*)(ws + off); off += (size_t)B * sizeof(float);
    int*   accNpos = (int*)(ws + off);   off += (size_t)B * sizeof(int);

    // one memset covers flags + keys + accumulators (contiguous)
    hipMemsetAsync(ws + flagOff, 0,
                   (size_t)B * A + (size_t)B * G * 8 + 5 * (size_t)B * 4, stream);

    int nch = G / GPER;
    kBestAnchor<<<dim3(B * nch * ASPLIT), 256, 0, stream>>>(anchors, gt, wsKey, A, G);
    int BG = B * G;
    kForce<<<dim3((BG + 255) / 256), 256, 0, stream>>>(wsKey, forcedFlag, A, G, BG);
    kMain<<<dim3(A / 256, B), 256, 0, stream>>>(bbox, conf, anchors, gt, forcedFlag, neg,
                                                accLoc, accFpos, accSiou, accNpos, A, G);
    kSelect<<<dim3(B), 1024, 0, stream>>>(neg, accNpos, accFpos, accConf, A);
    kFinal<<<1, 64, 0, stream>>>(accLoc, accConf, accSiou, accNpos, out, B);
}

// Round 3
// 143.221 us; speedup vs baseline: 2.0752x; 1.0838x over previous
//
#include <hip/hip_runtime.h>
#include <math.h>

#define IOU_TH 0.5f
#define EPSF 1e-6f
#define GPER 8
#define ASPLIT 8
#define NBIN 4096

__device__ __forceinline__ float sl1(float x) {
    float ax = fabsf(x);
    return ax < 1.f ? 0.5f * x * x : ax - 0.5f;
}

// ---------------- kernel 2: best anchor per (b,g), A split 8-way, merged via atomicMax ----
__global__ __launch_bounds__(256) void kBestAnchor(
    const float4* __restrict__ anchors, const float4* __restrict__ gt,
    unsigned long long* __restrict__ wsKey, int A, int G)
{
    int nch = G / GPER;
    int b   = blockIdx.x / (nch * ASPLIT);
    int r   = blockIdx.x % (nch * ASPLIT);
    int g0  = (r / ASPLIT) * GPER;
    int aChunk = A / ASPLIT;
    int a0  = (r % ASPLIT) * aChunk;

    float4 gb[GPER]; float ga[GPER];
#pragma unroll
    for (int j = 0; j < GPER; ++j) {
        gb[j] = gt[(size_t)b * G + g0 + j];
        ga[j] = (gb[j].z - gb[j].x) * (gb[j].w - gb[j].y);
    }
    float bi[GPER], bd[GPER]; int bx[GPER];
#pragma unroll
    for (int j = 0; j < GPER; ++j) { bi[j] = -1.f; bd[j] = 1.f; bx[j] = a0; }
    for (int a = a0 + threadIdx.x; a < a0 + aChunk; a += 256) {
        float4 ab = anchors[a];
        float aa = (ab.z - ab.x) * (ab.w - ab.y);
#pragma unroll
        for (int j = 0; j < GPER; ++j) {
            float wx = fmaxf(fminf(ab.z, gb[j].z) - fmaxf(ab.x, gb[j].x), 0.f);
            float wy = fmaxf(fminf(ab.w, gb[j].w) - fmaxf(ab.y, gb[j].y), 0.f);
            float inter = wx * wy;
            float den = aa + ga[j] - inter + EPSF;
            if (inter * bd[j] > bi[j] * den) { bi[j] = inter; bd[j] = den; bx[j] = a; }
        }
    }
    int lane = threadIdx.x & 63, wv = threadIdx.x >> 6;
    __shared__ float ri[4][GPER], rd[4][GPER]; __shared__ int rx[4][GPER];
#pragma unroll
    for (int j = 0; j < GPER; ++j) {
        float ci = bi[j], cd = bd[j]; int cx = bx[j];
        for (int off = 32; off > 0; off >>= 1) {
            float oi = __shfl_down(ci, off);
            float od = __shfl_down(cd, off);
            int   ox = __shfl_down(cx, off);
            if (lane + off < 64) {
                float lp = oi * cd, rp = ci * od;
                if (lp > rp || (lp == rp && ox < cx)) { ci = oi; cd = od; cx = ox; }
            }
        }
        if (lane == 0) { ri[wv][j] = ci; rd[wv][j] = cd; rx[wv][j] = cx; }
    }
    __syncthreads();
    if (threadIdx.x < GPER) {
        int j = threadIdx.x;
        float ci = ri[0][j], cd = rd[0][j]; int cx = rx[0][j];
        for (int w = 1; w < 4; ++w) {
            float oi = ri[w][j], od = rd[w][j]; int ox = rx[w][j];
            float lp = oi * cd, rp = ci * od;
            if (lp > rp || (lp == rp && ox < cx)) { ci = oi; cd = od; cx = ox; }
        }
        float iou = ci / cd;
        unsigned long long key =
            ((unsigned long long)__float_as_uint(iou) << 32) | (unsigned int)(~(unsigned int)cx);
        atomicMax(&wsKey[(size_t)b * G + g0 + j], key);
    }
}

// ---------------- kernel 2b: decode winners -> per-anchor forced flag ----------------
__global__ void kForce(const unsigned long long* __restrict__ wsKey,
                       unsigned char* __restrict__ flag, int A, int G, int BG)
{
    int i = blockIdx.x * 256 + threadIdx.x;
    if (i < BG) {
        unsigned long long k = wsKey[i];
        unsigned int idx = ~(unsigned int)(k & 0xFFFFFFFFull);
        int b = i / G;
        flag[(size_t)b * A + idx] = 1;
    }
}

// ---------------- kernel 3: per-anchor match + losses + neg-histogram ----------------
__global__ __launch_bounds__(256) void kMain(
    const float4* __restrict__ bbox, const float* __restrict__ conf,
    const float4* __restrict__ anchors, const float4* __restrict__ gt,
    const unsigned char* __restrict__ forcedFlag,
    float* __restrict__ neg, int* __restrict__ histC,
    float* __restrict__ accLoc, float* __restrict__ accFpos,
    float* __restrict__ accSiou, int* __restrict__ accNpos,
    int A, int G)
{
    __shared__ float4 sGt[128];
    int b = blockIdx.y;
    if (threadIdx.x < G) sGt[threadIdx.x] = gt[(size_t)b * G + threadIdx.x];
    __syncthreads();
    int a = blockIdx.x * 256 + threadIdx.x;   // A % 256 == 0
    float4 an = anchors[a];
    float aa = (an.z - an.x) * (an.w - an.y);

    // argmax over g: 4 independent chains (g mod 4)
    float bi[4], bd[4]; int bx[4];
#pragma unroll
    for (int c = 0; c < 4; ++c) { bi[c] = -1.f; bd[c] = 1.f; bx[c] = c; }
#pragma unroll 2
    for (int g = 0; g < G; g += 4) {
        float4 q0 = sGt[g], q1 = sGt[g + 1], q2 = sGt[g + 2], q3 = sGt[g + 3];
        {
            float gwa = (q0.z - q0.x) * (q0.w - q0.y);
            float wx = fmaxf(fminf(an.z, q0.z) - fmaxf(an.x, q0.x), 0.f);
            float wy = fmaxf(fminf(an.w, q0.w) - fmaxf(an.y, q0.y), 0.f);
            float inter = wx * wy;
            float den = aa + gwa - inter + EPSF;
            if (inter * bd[0] > bi[0] * den) { bi[0] = inter; bd[0] = den; bx[0] = g; }
        }
        {
            float gwa = (q1.z - q1.x) * (q1.w - q1.y);
            float wx = fmaxf(fminf(an.z, q1.z) - fmaxf(an.x, q1.x), 0.f);
            float wy = fmaxf(fminf(an.w, q1.w) - fmaxf(an.y, q1.y), 0.f);
            float inter = wx * wy;
            float den = aa + gwa - inter + EPSF;
            if (inter * bd[1] > bi[1] * den) { bi[1] = inter; bd[1] = den; bx[1] = g + 1; }
        }
        {
            float gwa = (q2.z - q2.x) * (q2.w - q2.y);
            float wx = fmaxf(fminf(an.z, q2.z) - fmaxf(an.x, q2.x), 0.f);
            float wy = fmaxf(fminf(an.w, q2.w) - fmaxf(an.y, q2.y), 0.f);
            float inter = wx * wy;
            float den = aa + gwa - inter + EPSF;
            if (inter * bd[2] > bi[2] * den) { bi[2] = inter; bd[2] = den; bx[2] = g + 2; }
        }
        {
            float gwa = (q3.z - q3.x) * (q3.w - q3.y);
            float wx = fmaxf(fminf(an.z, q3.z) - fmaxf(an.x, q3.x), 0.f);
            float wy = fmaxf(fminf(an.w, q3.w) - fmaxf(an.y, q3.y), 0.f);
            float inter = wx * wy;
            float den = aa + gwa - inter + EPSF;
            if (inter * bd[3] > bi[3] * den) { bi[3] = inter; bd[3] = den; bx[3] = g + 3; }
        }
    }
    float Bi = bi[0], Bd = bd[0]; int Bx = bx[0];
#pragma unroll
    for (int c = 1; c < 4; ++c) {
        float lp = bi[c] * Bd, rp = Bi * bd[c];
        if (lp > rp || (lp == rp && bx[c] < Bx)) { Bi = bi[c]; Bd = bd[c]; Bx = bx[c]; }
    }
    float best_iou = Bi / Bd;
    bool pos = (best_iou > IOU_TH) || (forcedFlag[(size_t)b * A + a] != 0);

    float4 p4 = bbox[(size_t)b * A + a];
    float4 m = sGt[Bx];
    float pa = (p4.z - p4.x) * (p4.w - p4.y);
    float ta = (m.z - m.x) * (m.w - m.y);
    float wx = fmaxf(fminf(p4.z, m.z) - fmaxf(p4.x, m.x), 0.f);
    float wy = fmaxf(fminf(p4.w, m.w) - fmaxf(p4.y, m.y), 0.f);
    float inter = wx * wy;
    float a_iou = inter / (pa + ta - inter + EPSF);
    float ex = fmaxf(fmaxf(p4.z, m.z) - fminf(p4.x, m.x), 0.f);
    float ey = fmaxf(fmaxf(p4.w, m.w) - fminf(p4.y, m.y), 0.f);
    float enc = ex * ey + EPSF;
    float uni = pa + ta - a_iou * pa * ta;
    float gl = 1.f - (a_iou - (enc - uni) / enc);
    float cl = sl1((p4.x + p4.z) * 0.5f - (m.x + m.z) * 0.5f)
             + sl1((p4.y + p4.w) * 0.5f - (m.y + m.w) * 0.5f);
    float szl = sl1((p4.z - p4.x) - (m.z - m.x)) + sl1((p4.w - p4.y) - (m.w - m.y));
    float box_loss = 0.5f * (cl + szl) + 0.5f * gl;
    float cp = conf[(size_t)b * A + a];
    float t = pos ? a_iou : 0.f;
    float pcl = fminf(fmaxf(cp, 1e-7f), 1.f - 1e-7f);
    float bce = -(t * logf(pcl) + (1.f - t) * log1pf(-pcl));
    float pt = (t > 0.f) ? cp : (1.f - cp);
    float om = 1.f - pt;
    float f = om * om * ((t > 0.f) ? 0.25f : 0.75f) * bce;

    neg[(size_t)b * A + a] = pos ? 0.f : f;
    if (!pos) {
        unsigned int u = __float_as_uint(f);
        atomicAdd(&histC[(size_t)b * NBIN + (u >> 19)], 1);
    }
    float vloc = pos ? box_loss : 0.f;
    float vf = pos ? f : 0.f;
    float vs = pos ? a_iou : 0.f;
    int vn = pos ? 1 : 0;
    int lane = threadIdx.x & 63, wv = threadIdx.x >> 6;
    for (int off = 32; off > 0; off >>= 1) {
        vloc += __shfl_down(vloc, off);
        vf   += __shfl_down(vf, off);
        vs   += __shfl_down(vs, off);
        vn   += __shfl_down(vn, off);
    }
    __shared__ float red[4][3]; __shared__ int redN[4];
    if (lane == 0) { red[wv][0] = vloc; red[wv][1] = vf; red[wv][2] = vs; redN[wv] = vn; }
    __syncthreads();
    if (threadIdx.x == 0) {
        float sl = 0.f, sf = 0.f, ss = 0.f; int sn = 0;
#pragma unroll
        for (int w = 0; w < 4; ++w) { sl += red[w][0]; sf += red[w][1]; ss += red[w][2]; sn += redN[w]; }
        atomicAdd(&accLoc[b], sl);
        atomicAdd(&accFpos[b], sf);
        atomicAdd(&accSiou[b], ss);
        atomicAdd(&accNpos[b], sn);
    }
}

// ---------------- kernel 4: top-k sum = hist suffix-scan + one A pass + candidate radix ----
__global__ __launch_bounds__(1024) void kSelect2(
    const float* __restrict__ neg, const int* __restrict__ histC,
    const int* __restrict__ accNpos, const float* __restrict__ accFpos,
    float* __restrict__ cand, float* __restrict__ accConf, int A)
{
    __shared__ int scanI[1024];
    __shared__ float scanF[1024];
    __shared__ int cnt[1024];
    __shared__ float sm[1024];
    __shared__ float redF[16];
    __shared__ int sh_cb, sh_rem, sh_n, sh_done;
    __shared__ float sh_res, sh_sumHigh;

    int b = blockIdx.x;
    int t = threadIdx.x;
    int npos = accNpos[b];
    int k = min(npos * 3, A - npos);
    if (k <= 0) { if (t == 0) accConf[b] = accFpos[b]; return; }

    // ---- level 0: cutoff bin via suffix scan of 4096-bin count hist ----
    int4 c4 = ((const int4*)(histC + (size_t)b * NBIN))[t];
    scanI[t] = c4.x + c4.y + c4.z + c4.w;
    __syncthreads();
    for (int off = 1; off < 1024; off <<= 1) {
        int v = (t + off < 1024) ? scanI[t + off] : 0;
        __syncthreads();
        scanI[t] += v;
        __syncthreads();
    }
    {
        int above = (t + 1 < 1024) ? scanI[t + 1] : 0;
        if (above < k && scanI[t] >= k) {     // crossing in my 4 bins (unique thread)
            int carr[4] = {c4.x, c4.y, c4.z, c4.w};
            int cum = above;
            for (int j = 3; j >= 0; --j) {
                cum += carr[j];
                if (cum >= k) { sh_cb = 4 * t + j; sh_rem = k - (cum - carr[j]); break; }
            }
            sh_n = 0; sh_res = 0.f; sh_done = 0;
        }
    }
    __syncthreads();
    int cb = sh_cb;

    // ---- one pass over A: sum bins>cb, gather bin==cb candidates ----
    float localSum = 0.f;
    const float4* nb4 = (const float4*)(neg + (size_t)b * A);
    float* cb_buf = cand + (size_t)b * A;
    for (int i = t; i < A / 4; i += 1024) {
        float4 v = nb4[i];
        float vv[4] = {v.x, v.y, v.z, v.w};
#pragma unroll
        for (int j = 0; j < 4; ++j) {
            int bin = (int)(__float_as_uint(vv[j]) >> 19);
            if (bin > cb) localSum += vv[j];
            else if (bin == cb) {
                int idx = atomicAdd(&sh_n, 1);
                cb_buf[idx] = vv[j];
            }
        }
    }
    {
        int lane = t & 63, wv = t >> 6;
        for (int off = 32; off > 0; off >>= 1) localSum += __shfl_down(localSum, off);
        if (lane == 0) redF[wv] = localSum;
    }
    __syncthreads();
    if (t == 0) {
        float tot = 0.f;
        for (int w = 0; w < 16; ++w) tot += redF[w];
        sh_sumHigh = tot;
    }
    __syncthreads();
    int n = sh_n;
    int rem = sh_rem;

    // ---- level 1: bits 18..9 of candidates ----
    cnt[t] = 0; sm[t] = 0.f;
    __syncthreads();
    for (int i = t; i < n; i += 1024) {
        float v = cb_buf[i];
        int bin = (int)((__float_as_uint(v) >> 9) & 1023u);
        atomicAdd(&cnt[bin], 1);
        atomicAdd(&sm[bin], v);
    }
    __syncthreads();
    scanI[t] = cnt[t]; scanF[t] = sm[t];
    __syncthreads();
    for (int off = 1; off < 1024; off <<= 1) {
        int vi = 0; float vf = 0.f;
        if (t + off < 1024) { vi = scanI[t + off]; vf = scanF[t + off]; }
        __syncthreads();
        scanI[t] += vi; scanF[t] += vf;
        __syncthreads();
    }
    {
        int aboveC = (t + 1 < 1024) ? scanI[t + 1] : 0;
        if (aboveC < rem && scanI[t] >= rem) {
            float aboveS = (t + 1 < 1024) ? scanF[t + 1] : 0.f;
            int need = rem - aboveC;
            if (cnt[t] == need) { sh_res += aboveS + sm[t]; sh_done = 1; }
            else { sh_res += aboveS; sh_rem = need; sh_cb = t; }
        }
    }
    __syncthreads();
    if (!sh_done) {
        int cb2 = sh_cb;
        rem = sh_rem;
        // ---- level 2: bits 8..0, filtered on level-1 bin ----
        if (t < 512) { cnt[t] = 0; sm[t] = 0.f; }
        __syncthreads();
        for (int i = t; i < n; i += 1024) {
            float v = cb_buf[i];
            unsigned int u = __float_as_uint(v);
            if ((int)((u >> 9) & 1023u) == cb2) {
                int bin = (int)(u & 511u);
                atomicAdd(&cnt[bin], 1);
                atomicAdd(&sm[bin], v);
            }
        }
        __syncthreads();
        scanI[t] = (t < 512) ? cnt[t] : 0;
        scanF[t] = (t < 512) ? sm[t] : 0.f;
        __syncthreads();
        for (int off = 1; off < 512; off <<= 1) {
            int vi = 0; float vf = 0.f;
            if (t + off < 512) { vi = scanI[t + off]; vf = scanF[t + off]; }
            __syncthreads();
            if (t < 512) { scanI[t] += vi; scanF[t] += vf; }
            __syncthreads();
        }
        if (t < 512) {
            int aboveC = (t + 1 < 512) ? scanI[t + 1] : 0;
            if (aboveC < rem && scanI[t] >= rem) {
                float aboveS = (t + 1 < 512) ? scanF[t + 1] : 0.f;
                int need = rem - aboveC;
                if (cnt[t] == need) {
                    sh_res += aboveS + sm[t];
                } else {
                    // all 32 bits identical in this bin -> exact value
                    unsigned int u = ((unsigned int)cb << 19) | ((unsigned int)cb2 << 9) | (unsigned int)t;
                    sh_res += aboveS + (float)need * __uint_as_float(u);
                }
            }
        }
        __syncthreads();
    }
    if (t == 0) accConf[b] = sh_sumHigh + sh_res + accFpos[b];
}

// ---------------- kernel 5: final reduce ----------------
__global__ void kFinal(const float* __restrict__ accLoc, const float* __restrict__ accConf,
                       const float* __restrict__ accSiou, const int* __restrict__ accNpos,
                       float* __restrict__ out, int B)
{
    int lane = threadIdx.x;
    float loc = 0.f, cf = 0.f, si = 0.f; int np = 0;
    if (lane < B) { loc = accLoc[lane]; cf = accConf[lane]; si = accSiou[lane]; np = accNpos[lane]; }
    for (int off = 32; off > 0; off >>= 1) {
        loc += __shfl_down(loc, off);
        cf  += __shfl_down(cf, off);
        si  += __shfl_down(si, off);
        np  += __shfl_down(np, off);
    }
    if (lane == 0) {
        float denom = fmaxf(1.f, (float)np);
        float tl = loc / denom, tc = cf / denom;
        out[0] = tl + tc;
        out[1] = tc;
        out[2] = tl;
        out[3] = si / denom;
    }
}

extern "C" void kernel_launch(void* const* d_in, const int* in_sizes, int n_in,
                              void* d_out, int out_size, void* d_ws, size_t ws_size,
                              hipStream_t stream)
{
    const float4* bbox    = (const float4*)d_in[0];
    const float*  conf    = (const float*)d_in[1];
    const float4* anchors = (const float4*)d_in[2];
    const float4* gt      = (const float4*)d_in[3];
    int A = in_sizes[2] / 4;
    int B = in_sizes[1] / A;
    int G = in_sizes[3] / (4 * B);
    float* out = (float*)d_out;

    char* ws = (char*)d_ws;
    size_t off = 0;
    float* neg  = (float*)(ws + off); off += (size_t)B * A * sizeof(float);
    float* cand = (float*)(ws + off); off += (size_t)B * A * sizeof(float);
    size_t zOff = off;                                    // zeroed region starts here
    unsigned char* forcedFlag = (unsigned char*)(ws + off); off += (size_t)B * A;
    unsigned long long* wsKey = (unsigned long long*)(ws + off); off += (size_t)B * G * 8;
    int* histC = (int*)(ws + off); off += (size_t)B * NBIN * sizeof(int);
    float* accLoc  = (float*)(ws + off); off += (size_t)B * sizeof(float);
    float* accFpos = (float*)(ws + off); off += (size_t)B * sizeof(float);
    float* accSiou = (float*)(ws + off); off += (size_t)B * sizeof(float);
    float* accConf = (float*)(ws + off); off += (size_t)B * sizeof(float);
    int*   accNpos = (int*)(ws + off);   off += (size_t)B * sizeof(int);
    size_t zBytes = off - zOff;

    hipMemsetAsync(ws + zOff, 0, zBytes, stream);

    int nch = G / GPER;
    kBestAnchor<<<dim3(B * nch * ASPLIT), 256, 0, stream>>>(anchors, gt, wsKey, A, G);
    int BG = B * G;
    kForce<<<dim3((BG + 255) / 256), 256, 0, stream>>>(wsKey, forcedFlag, A, G, BG);
    kMain<<<dim3(A / 256, B), 256, 0, stream>>>(bbox, conf, anchors, gt, forcedFlag, neg, histC,
                                                accLoc, accFpos, accSiou, accNpos, A, G);
    kSelect2<<<dim3(B), 1024, 0, stream>>>(neg, histC, accNpos, accFpos, cand, accConf, A);
    kFinal<<<1, 64, 0, stream>>>(accLoc, accConf, accSiou, accNpos, out, B);
}

// Round 4
// 95.978 us; speedup vs baseline: 3.0967x; 1.4922x over previous
//
#include <hip/hip_runtime.h>
#include <math.h>

#define IOU_TH 0.5f
#define EPSF 1e-6f
#define GPER 8
#define ASPLIT 8
#define NBIN 4096

__device__ __forceinline__ float sl1(float x) {
    float ax = fabsf(x);
    return ax < 1.f ? 0.5f * x * x : ax - 0.5f;
}

// ---------------- kernel 2: best anchor per (b,g), A split 8-way, merged via atomicMax ----
__global__ __launch_bounds__(256) void kBestAnchor(
    const float4* __restrict__ anchors, const float4* __restrict__ gt,
    unsigned long long* __restrict__ wsKey, int A, int G)
{
    int nch = G / GPER;
    int b   = blockIdx.x / (nch * ASPLIT);
    int r   = blockIdx.x % (nch * ASPLIT);
    int g0  = (r / ASPLIT) * GPER;
    int aChunk = A / ASPLIT;
    int a0  = (r % ASPLIT) * aChunk;

    float4 gb[GPER]; float ga[GPER];
#pragma unroll
    for (int j = 0; j < GPER; ++j) {
        gb[j] = gt[(size_t)b * G + g0 + j];
        ga[j] = (gb[j].z - gb[j].x) * (gb[j].w - gb[j].y);
    }
    float bi[GPER], bd[GPER]; int bx[GPER];
#pragma unroll
    for (int j = 0; j < GPER; ++j) { bi[j] = -1.f; bd[j] = 1.f; bx[j] = a0; }
    for (int a = a0 + threadIdx.x; a < a0 + aChunk; a += 256) {
        float4 ab = anchors[a];
        float aa = (ab.z - ab.x) * (ab.w - ab.y);
#pragma unroll
        for (int j = 0; j < GPER; ++j) {
            float wx = fmaxf(fminf(ab.z, gb[j].z) - fmaxf(ab.x, gb[j].x), 0.f);
            float wy = fmaxf(fminf(ab.w, gb[j].w) - fmaxf(ab.y, gb[j].y), 0.f);
            float inter = wx * wy;
            float den = aa + ga[j] - inter + EPSF;
            if (inter * bd[j] > bi[j] * den) { bi[j] = inter; bd[j] = den; bx[j] = a; }
        }
    }
    int lane = threadIdx.x & 63, wv = threadIdx.x >> 6;
    __shared__ float ri[4][GPER], rd[4][GPER]; __shared__ int rx[4][GPER];
#pragma unroll
    for (int j = 0; j < GPER; ++j) {
        float ci = bi[j], cd = bd[j]; int cx = bx[j];
        for (int off = 32; off > 0; off >>= 1) {
            float oi = __shfl_down(ci, off);
            float od = __shfl_down(cd, off);
            int   ox = __shfl_down(cx, off);
            if (lane + off < 64) {
                float lp = oi * cd, rp = ci * od;
                if (lp > rp || (lp == rp && ox < cx)) { ci = oi; cd = od; cx = ox; }
            }
        }
        if (lane == 0) { ri[wv][j] = ci; rd[wv][j] = cd; rx[wv][j] = cx; }
    }
    __syncthreads();
    if (threadIdx.x < GPER) {
        int j = threadIdx.x;
        float ci = ri[0][j], cd = rd[0][j]; int cx = rx[0][j];
        for (int w = 1; w < 4; ++w) {
            float oi = ri[w][j], od = rd[w][j]; int ox = rx[w][j];
            float lp = oi * cd, rp = ci * od;
            if (lp > rp || (lp == rp && ox < cx)) { ci = oi; cd = od; cx = ox; }
        }
        float iou = ci / cd;
        unsigned long long key =
            ((unsigned long long)__float_as_uint(iou) << 32) | (unsigned int)(~(unsigned int)cx);
        atomicMax(&wsKey[(size_t)b * G + g0 + j], key);
    }
}

// ---------------- kernel 2b: decode winners -> per-anchor forced flag ----------------
__global__ void kForce(const unsigned long long* __restrict__ wsKey,
                       unsigned char* __restrict__ flag, int A, int G, int BG)
{
    int i = blockIdx.x * 256 + threadIdx.x;
    if (i < BG) {
        unsigned long long k = wsKey[i];
        unsigned int idx = ~(unsigned int)(k & 0xFFFFFFFFull);
        int b = i / G;
        flag[(size_t)b * A + idx] = 1;
    }
}

// ---------------- kernel 3: per-anchor match + losses + LDS-staged neg-histogram ----
__global__ __launch_bounds__(256) void kMain(
    const float4* __restrict__ bbox, const float* __restrict__ conf,
    const float4* __restrict__ anchors, const float4* __restrict__ gt,
    const unsigned char* __restrict__ forcedFlag,
    float* __restrict__ neg, int* __restrict__ histC,
    float* __restrict__ accLoc, float* __restrict__ accFpos,
    float* __restrict__ accSiou, int* __restrict__ accNpos,
    int A, int G)
{
    __shared__ float4 sGt[64];
    __shared__ float sGa[64];
    __shared__ int sHist[NBIN];
    __shared__ float red[4][3]; __shared__ int redN[4];
    int b = blockIdx.y;
    for (int i = threadIdx.x; i < NBIN; i += 256) sHist[i] = 0;
    if (threadIdx.x < G) {
        float4 g = gt[(size_t)b * G + threadIdx.x];
        sGt[threadIdx.x] = g;
        sGa[threadIdx.x] = (g.z - g.x) * (g.w - g.y);
    }
    __syncthreads();
    int a = blockIdx.x * 256 + threadIdx.x;   // A % 256 == 0
    float4 an = anchors[a];
    float aa = (an.z - an.x) * (an.w - an.y);

    // argmax over g: 4 independent chains (g mod 4), areas staged in LDS
    float bi[4], bd[4]; int bx[4];
#pragma unroll
    for (int c = 0; c < 4; ++c) { bi[c] = -1.f; bd[c] = 1.f; bx[c] = c; }
#pragma unroll 2
    for (int g = 0; g < G; g += 4) {
        float4 q0 = sGt[g], q1 = sGt[g + 1], q2 = sGt[g + 2], q3 = sGt[g + 3];
        float4 ga4 = *(const float4*)&sGa[g];
        {
            float wx = fmaxf(fminf(an.z, q0.z) - fmaxf(an.x, q0.x), 0.f);
            float wy = fmaxf(fminf(an.w, q0.w) - fmaxf(an.y, q0.y), 0.f);
            float inter = wx * wy;
            float den = aa + ga4.x - inter + EPSF;
            if (inter * bd[0] > bi[0] * den) { bi[0] = inter; bd[0] = den; bx[0] = g; }
        }
        {
            float wx = fmaxf(fminf(an.z, q1.z) - fmaxf(an.x, q1.x), 0.f);
            float wy = fmaxf(fminf(an.w, q1.w) - fmaxf(an.y, q1.y), 0.f);
            float inter = wx * wy;
            float den = aa + ga4.y - inter + EPSF;
            if (inter * bd[1] > bi[1] * den) { bi[1] = inter; bd[1] = den; bx[1] = g + 1; }
        }
        {
            float wx = fmaxf(fminf(an.z, q2.z) - fmaxf(an.x, q2.x), 0.f);
            float wy = fmaxf(fminf(an.w, q2.w) - fmaxf(an.y, q2.y), 0.f);
            float inter = wx * wy;
            float den = aa + ga4.z - inter + EPSF;
            if (inter * bd[2] > bi[2] * den) { bi[2] = inter; bd[2] = den; bx[2] = g + 2; }
        }
        {
            float wx = fmaxf(fminf(an.z, q3.z) - fmaxf(an.x, q3.x), 0.f);
            float wy = fmaxf(fminf(an.w, q3.w) - fmaxf(an.y, q3.y), 0.f);
            float inter = wx * wy;
            float den = aa + ga4.w - inter + EPSF;
            if (inter * bd[3] > bi[3] * den) { bi[3] = inter; bd[3] = den; bx[3] = g + 3; }
        }
    }
    float Bi = bi[0], Bd = bd[0]; int Bx = bx[0];
#pragma unroll
    for (int c = 1; c < 4; ++c) {
        float lp = bi[c] * Bd, rp = Bi * bd[c];
        if (lp > rp || (lp == rp && bx[c] < Bx)) { Bi = bi[c]; Bd = bd[c]; Bx = bx[c]; }
    }
    float best_iou = Bi / Bd;
    bool pos = (best_iou > IOU_TH) || (forcedFlag[(size_t)b * A + a] != 0);

    float4 p4 = bbox[(size_t)b * A + a];
    float4 m = sGt[Bx];
    float pa = (p4.z - p4.x) * (p4.w - p4.y);
    float ta = (m.z - m.x) * (m.w - m.y);
    float wx = fmaxf(fminf(p4.z, m.z) - fmaxf(p4.x, m.x), 0.f);
    float wy = fmaxf(fminf(p4.w, m.w) - fmaxf(p4.y, m.y), 0.f);
    float inter = wx * wy;
    float a_iou = inter / (pa + ta - inter + EPSF);
    float ex = fmaxf(fmaxf(p4.z, m.z) - fminf(p4.x, m.x), 0.f);
    float ey = fmaxf(fmaxf(p4.w, m.w) - fminf(p4.y, m.y), 0.f);
    float enc = ex * ey + EPSF;
    float uni = pa + ta - a_iou * pa * ta;
    float gl = 1.f - (a_iou - (enc - uni) / enc);
    float cl = sl1((p4.x + p4.z) * 0.5f - (m.x + m.z) * 0.5f)
             + sl1((p4.y + p4.w) * 0.5f - (m.y + m.w) * 0.5f);
    float szl = sl1((p4.z - p4.x) - (m.z - m.x)) + sl1((p4.w - p4.y) - (m.w - m.y));
    float box_loss = 0.5f * (cl + szl) + 0.5f * gl;
    float cp = conf[(size_t)b * A + a];
    float t = pos ? a_iou : 0.f;
    float pcl = fminf(fmaxf(cp, 1e-7f), 1.f - 1e-7f);
    float bce = -(t * logf(pcl) + (1.f - t) * log1pf(-pcl));
    float pt = (t > 0.f) ? cp : (1.f - cp);
    float om = 1.f - pt;
    float f = om * om * ((t > 0.f) ? 0.25f : 0.75f) * bce;

    neg[(size_t)b * A + a] = pos ? 0.f : f;
    if (!pos) {
        unsigned int u = __float_as_uint(f);
        atomicAdd(&sHist[u >> 19], 1);          // LDS histogram (low contention per block)
    }
    float vloc = pos ? box_loss : 0.f;
    float vf = pos ? f : 0.f;
    float vs = pos ? a_iou : 0.f;
    int vn = pos ? 1 : 0;
    int lane = threadIdx.x & 63, wv = threadIdx.x >> 6;
    for (int off = 32; off > 0; off >>= 1) {
        vloc += __shfl_down(vloc, off);
        vf   += __shfl_down(vf, off);
        vs   += __shfl_down(vs, off);
        vn   += __shfl_down(vn, off);
    }
    if (lane == 0) { red[wv][0] = vloc; red[wv][1] = vf; red[wv][2] = vs; redN[wv] = vn; }
    __syncthreads();   // also orders all sHist atomics before flush
    if (threadIdx.x == 0) {
        float sl = 0.f, sf = 0.f, ss = 0.f; int sn = 0;
#pragma unroll
        for (int w = 0; w < 4; ++w) { sl += red[w][0]; sf += red[w][1]; ss += red[w][2]; sn += redN[w]; }
        atomicAdd(&accLoc[b], sl);
        atomicAdd(&accFpos[b], sf);
        atomicAdd(&accSiou[b], ss);
        atomicAdd(&accNpos[b], sn);
    }
    // flush non-zero histogram bins (max ~256 per block)
    int* hb = histC + (size_t)b * NBIN;
    for (int i = threadIdx.x; i < NBIN; i += 256) {
        int c = sHist[i];
        if (c) atomicAdd(&hb[i], c);
    }
}

// ---------------- kernel 4: top-k sum = hist suffix-scan + one A pass + candidate radix ----
__global__ __launch_bounds__(1024) void kSelect2(
    const float* __restrict__ neg, const int* __restrict__ histC,
    const int* __restrict__ accNpos, const float* __restrict__ accFpos,
    float* __restrict__ cand, float* __restrict__ accConf, int A)
{
    __shared__ int scanI[1024];
    __shared__ float scanF[1024];
    __shared__ int cnt[1024];
    __shared__ float sm[1024];
    __shared__ float redF[16];
    __shared__ int sh_cb, sh_rem, sh_n, sh_done;
    __shared__ float sh_res, sh_sumHigh;

    int b = blockIdx.x;
    int t = threadIdx.x;
    int npos = accNpos[b];
    int k = min(npos * 3, A - npos);
    if (k <= 0) { if (t == 0) accConf[b] = accFpos[b]; return; }

    // ---- level 0: cutoff bin via suffix scan of 4096-bin count hist ----
    int4 c4 = ((const int4*)(histC + (size_t)b * NBIN))[t];
    scanI[t] = c4.x + c4.y + c4.z + c4.w;
    __syncthreads();
    for (int off = 1; off < 1024; off <<= 1) {
        int v = (t + off < 1024) ? scanI[t + off] : 0;
        __syncthreads();
        scanI[t] += v;
        __syncthreads();
    }
    {
        int above = (t + 1 < 1024) ? scanI[t + 1] : 0;
        if (above < k && scanI[t] >= k) {
            int carr[4] = {c4.x, c4.y, c4.z, c4.w};
            int cum = above;
            for (int j = 3; j >= 0; --j) {
                cum += carr[j];
                if (cum >= k) { sh_cb = 4 * t + j; sh_rem = k - (cum - carr[j]); break; }
            }
            sh_n = 0; sh_res = 0.f; sh_done = 0;
        }
    }
    __syncthreads();
    int cb = sh_cb;

    // ---- one pass over A: sum bins>cb, gather bin==cb candidates ----
    float localSum = 0.f;
    const float4* nb4 = (const float4*)(neg + (size_t)b * A);
    float* cb_buf = cand + (size_t)b * A;
    for (int i = t; i < A / 4; i += 1024) {
        float4 v = nb4[i];
        float vv[4] = {v.x, v.y, v.z, v.w};
#pragma unroll
        for (int j = 0; j < 4; ++j) {
            int bin = (int)(__float_as_uint(vv[j]) >> 19);
            if (bin > cb) localSum += vv[j];
            else if (bin == cb) {
                int idx = atomicAdd(&sh_n, 1);
                cb_buf[idx] = vv[j];
            }
        }
    }
    {
        int lane = t & 63, wv = t >> 6;
        for (int off = 32; off > 0; off >>= 1) localSum += __shfl_down(localSum, off);
        if (lane == 0) redF[wv] = localSum;
    }
    __syncthreads();
    if (t == 0) {
        float tot = 0.f;
        for (int w = 0; w < 16; ++w) tot += redF[w];
        sh_sumHigh = tot;
    }
    __syncthreads();
    int n = sh_n;
    int rem = sh_rem;

    // ---- level 1: bits 18..9 of candidates ----
    cnt[t] = 0; sm[t] = 0.f;
    __syncthreads();
    for (int i = t; i < n; i += 1024) {
        float v = cb_buf[i];
        int bin = (int)((__float_as_uint(v) >> 9) & 1023u);
        atomicAdd(&cnt[bin], 1);
        atomicAdd(&sm[bin], v);
    }
    __syncthreads();
    scanI[t] = cnt[t]; scanF[t] = sm[t];
    __syncthreads();
    for (int off = 1; off < 1024; off <<= 1) {
        int vi = 0; float vf = 0.f;
        if (t + off < 1024) { vi = scanI[t + off]; vf = scanF[t + off]; }
        __syncthreads();
        scanI[t] += vi; scanF[t] += vf;
        __syncthreads();
    }
    {
        int aboveC = (t + 1 < 1024) ? scanI[t + 1] : 0;
        if (aboveC < rem && scanI[t] >= rem) {
            float aboveS = (t + 1 < 1024) ? scanF[t + 1] : 0.f;
            int need = rem - aboveC;
            if (cnt[t] == need) { sh_res += aboveS + sm[t]; sh_done = 1; }
            else { sh_res += aboveS; sh_rem = need; sh_cb = t; }
        }
    }
    __syncthreads();
    if (!sh_done) {
        int cb2 = sh_cb;
        rem = sh_rem;
        if (t < 512) { cnt[t] = 0; sm[t] = 0.f; }
        __syncthreads();
        for (int i = t; i < n; i += 1024) {
            float v = cb_buf[i];
            unsigned int u = __float_as_uint(v);
            if ((int)((u >> 9) & 1023u) == cb2) {
                int bin = (int)(u & 511u);
                atomicAdd(&cnt[bin], 1);
                atomicAdd(&sm[bin], v);
            }
        }
        __syncthreads();
        scanI[t] = (t < 512) ? cnt[t] : 0;
        scanF[t] = (t < 512) ? sm[t] : 0.f;
        __syncthreads();
        for (int off = 1; off < 512; off <<= 1) {
            int vi = 0; float vf = 0.f;
            if (t + off < 512) { vi = scanI[t + off]; vf = scanF[t + off]; }
            __syncthreads();
            if (t < 512) { scanI[t] += vi; scanF[t] += vf; }
            __syncthreads();
        }
        if (t < 512) {
            int aboveC = (t + 1 < 512) ? scanI[t + 1] : 0;
            if (aboveC < rem && scanI[t] >= rem) {
                float aboveS = (t + 1 < 512) ? scanF[t + 1] : 0.f;
                int need = rem - aboveC;
                if (cnt[t] == need) {
                    sh_res += aboveS + sm[t];
                } else {
                    unsigned int u = ((unsigned int)cb << 19) | ((unsigned int)cb2 << 9) | (unsigned int)t;
                    sh_res += aboveS + (float)need * __uint_as_float(u);
                }
            }
        }
        __syncthreads();
    }
    if (t == 0) accConf[b] = sh_sumHigh + sh_res + accFpos[b];
}

// ---------------- kernel 5: final reduce ----------------
__global__ void kFinal(const float* __restrict__ accLoc, const float* __restrict__ accConf,
                       const float* __restrict__ accSiou, const int* __restrict__ accNpos,
                       float* __restrict__ out, int B)
{
    int lane = threadIdx.x;
    float loc = 0.f, cf = 0.f, si = 0.f; int np = 0;
    if (lane < B) { loc = accLoc[lane]; cf = accConf[lane]; si = accSiou[lane]; np = accNpos[lane]; }
    for (int off = 32; off > 0; off >>= 1) {
        loc += __shfl_down(loc, off);
        cf  += __shfl_down(cf, off);
        si  += __shfl_down(si, off);
        np  += __shfl_down(np, off);
    }
    if (lane == 0) {
        float denom = fmaxf(1.f, (float)np);
        float tl = loc / denom, tc = cf / denom;
        out[0] = tl + tc;
        out[1] = tc;
        out[2] = tl;
        out[3] = si / denom;
    }
}

extern "C" void kernel_launch(void* const* d_in, const int* in_sizes, int n_in,
                              void* d_out, int out_size, void* d_ws, size_t ws_size,
                              hipStream_t stream)
{
    const float4* bbox    = (const float4*)d_in[0];
    const float*  conf    = (const float*)d_in[1];
    const float4* anchors = (const float4*)d_in[2];
    const float4* gt      = (const float4*)d_in[3];
    int A = in_sizes[2] / 4;
    int B = in_sizes[1] / A;
    int G = in_sizes[3] / (4 * B);
    float* out = (float*)d_out;

    char* ws = (char*)d_ws;
    size_t off = 0;
    float* neg  = (float*)(ws + off); off += (size_t)B * A * sizeof(float);
    float* cand = (float*)(ws + off); off += (size_t)B * A * sizeof(float);
    size_t zOff = off;
    unsigned char* forcedFlag = (unsigned char*)(ws + off); off += (size_t)B * A;
    unsigned long long* wsKey = (unsigned long long*)(ws + off); off += (size_t)B * G * 8;
    int* histC = (int*)(ws + off); off += (size_t)B * NBIN * sizeof(int);
    float* accLoc  = (float*)(ws + off); off += (size_t)B * sizeof(float);
    float* accFpos = (float*)(ws + off); off += (size_t)B * sizeof(float);
    float* accSiou = (float*)(ws + off); off += (size_t)B * sizeof(float);
    float* accConf = (float*)(ws + off); off += (size_t)B * sizeof(float);
    int*   accNpos = (int*)(ws + off);   off += (size_t)B * sizeof(int);
    size_t zBytes = off - zOff;

    hipMemsetAsync(ws + zOff, 0, zBytes, stream);

    int nch = G / GPER;
    kBestAnchor<<<dim3(B * nch * ASPLIT), 256, 0, stream>>>(anchors, gt, wsKey, A, G);
    int BG = B * G;
    kForce<<<dim3((BG + 255) / 256), 256, 0, stream>>>(wsKey, forcedFlag, A, G, BG);
    kMain<<<dim3(A / 256, B), 256, 0, stream>>>(bbox, conf, anchors, gt, forcedFlag, neg, histC,
                                                accLoc, accFpos, accSiou, accNpos, A, G);
    kSelect2<<<dim3(B), 1024, 0, stream>>>(neg, histC, accNpos, accFpos, cand, accConf, A);
    kFinal<<<1, 64, 0, stream>>>(accLoc, accConf, accSiou, accNpos, out, B);
}